// Round 8
// baseline (648.109 us; speedup 1.0000x reference)
//
#include <hip/hip_runtime.h>

// B=256, DIM=1024, H=16, HD=64, DS=4, NL=64, NKV=256
// Pipeline (5 launches):
//  1. fused_pre: Wq/Wk/Wv->bf16, wob = bf16(g_out⊙Wo), LN(latents)->lnl, LN(x)->lnx
//  2. gemm_qkv: merged [lnx @ [Wk;Wv]^T -> K,(V^T)] + [lnl @ Wq^T -> Q]   (32x32x16 MFMA)
//  3. attn per (b,h): S=Q K^T*0.125, mask (col>>2)<=row, softmax, O=P~ V -> ao
//  4. stats: row mean/rstd of ao  +  u[c]=Σ g_out·Wo[c,:], w[c]=Σ b_out·Wo[c,:]
//  5. gemm_out: raw ao @ wob^T, epilogue out = rstd*acc - rstd*mean*u + w + bo + resid
//     (LN commuted through the GEMM: LN(a)@Wo^T = rstd*(a@(g⊙Wo)^T) - rstd*mean*u + w)
//
// GEMM core: 256x256 tile, BK=64, 8 waves (2Mx4N), 128KiB dbuf LDS, 4-phase
// double-barrier schedule, counted vmcnt(4), chunk-XOR swizzle, setprio,
// bijective chunked XCD swizzle. R8: 32x32x16 MFMA (C/D: col=lane&31,
// row=(reg&3)+8*(reg>>2)+4*(lane>>5); A/B: row=lane&31, k=(lane>>5)*8+e).
// fp8 QKV GEMM tried (R6): FAILS accuracy fundamentally (absmax 0.37 > 0.149).

typedef unsigned short u16;
typedef float f32x4 __attribute__((ext_vector_type(4)));
typedef float f32x16 __attribute__((ext_vector_type(16)));
typedef short bf16x8 __attribute__((ext_vector_type(8)));
typedef u16 u16x4 __attribute__((ext_vector_type(4)));

#define DEV __device__ __forceinline__

DEV u16 f2bf(float f) {
  union { float f; unsigned int u; } c; c.f = f;
  unsigned int u = c.u;
  u += 0x7fffu + ((u >> 16) & 1u);   // RNE
  return (u16)(u >> 16);
}
DEV float bf2f(u16 u) {
  union { unsigned int u; float f; } c; c.u = ((unsigned int)u) << 16; return c.f;
}
DEV f32x4 mfma16(bf16x8 a, bf16x8 b, f32x4 c) {
  return __builtin_amdgcn_mfma_f32_16x16x32_bf16(a, b, c, 0, 0, 0);
}
DEV f32x16 mfma32(bf16x8 a, bf16x8 b, f32x16 c) {
  return __builtin_amdgcn_mfma_f32_32x32x16_bf16(a, b, c, 0, 0, 0);
}
DEV void gl16(const void* g, void* l) {
  __builtin_amdgcn_global_load_lds((const __attribute__((address_space(1))) void*)g,
                                   (__attribute__((address_space(3))) void*)l, 16, 0, 0);
}

// ---------------- LN row helper: 1024 elems, 256 threads ----------------
DEV void ln_row_f32(const float* __restrict__ srcrow, const float* __restrict__ g,
                    const float* __restrict__ bta, u16* __restrict__ dstrow,
                    int tid, float* red) {
  const float4 r = *((const float4*)srcrow + tid);
  float v[4] = {r.x, r.y, r.z, r.w};
  float s = v[0] + v[1] + v[2] + v[3];
  float q = v[0]*v[0] + v[1]*v[1] + v[2]*v[2] + v[3]*v[3];
#pragma unroll
  for (int off = 32; off; off >>= 1) {
    s += __shfl_xor(s, off, 64);
    q += __shfl_xor(q, off, 64);
  }
  if ((tid & 63) == 0) { red[(tid >> 6) * 2] = s; red[(tid >> 6) * 2 + 1] = q; }
  __syncthreads();
  s = red[0] + red[2] + red[4] + red[6];
  q = red[1] + red[3] + red[5] + red[7];
  const float mean = s * (1.f / 1024.f);
  const float rstd = rsqrtf(q * (1.f / 1024.f) - mean * mean + 1e-5f);
  const float4 gv = *((const float4*)g + tid);
  const float4 bv = *((const float4*)bta + tid);
  u16x4 o;
  o[0] = f2bf((v[0] - mean) * rstd * gv.x + bv.x);
  o[1] = f2bf((v[1] - mean) * rstd * gv.y + bv.y);
  o[2] = f2bf((v[2] - mean) * rstd * gv.z + bv.z);
  o[3] = f2bf((v[3] - mean) * rstd * gv.w + bv.w);
  *((u16x4*)dstrow + tid) = o;
}

// ---------------- fused: weight cvt + LN(latents) + LN(x) ----------------
// g<3: Wq/Wk/Wv -> bf16 at wout + g*1M. g==3: wob = bf16(g_out[k]*Wo[c,k]).
__global__ __launch_bounds__(256) void fused_pre(const float* __restrict__ w0,
                                                 const float* __restrict__ w1,
                                                 const float* __restrict__ w2,
                                                 const float* __restrict__ w3,
                                                 u16* __restrict__ wout,
                                                 u16* __restrict__ wob,
                                                 const float* __restrict__ g_out,
                                                 const float* __restrict__ lat,
                                                 const float* __restrict__ g_l,
                                                 const float* __restrict__ b_l,
                                                 u16* __restrict__ lnl,
                                                 const float* __restrict__ x,
                                                 const float* __restrict__ g_x,
                                                 const float* __restrict__ b_x,
                                                 u16* __restrict__ lnx) {
  __shared__ float red[8];
  const int bid = blockIdx.x, tid = threadIdx.x;
  if (bid < 4096) {  // weight convert
    const int g = bid >> 10;
    const int i = ((bid & 1023) * 256 + tid) * 4;
    if (g < 3) {
      const float* src = (g == 0) ? w0 : (g == 1) ? w1 : w2;
      const float4 v = *(const float4*)(src + i);
      u16x4 o; o[0] = f2bf(v.x); o[1] = f2bf(v.y); o[2] = f2bf(v.z); o[3] = f2bf(v.w);
      *(u16x4*)(wout + (size_t)g * 1048576 + i) = o;
    } else {  // row c = bid&1023 of Wo; fold g_out into the weight
      const float4 v = *(const float4*)(w3 + i);
      const float4 gv = *((const float4*)g_out + tid);
      u16x4 o;
      o[0] = f2bf(gv.x * v.x); o[1] = f2bf(gv.y * v.y);
      o[2] = f2bf(gv.z * v.z); o[3] = f2bf(gv.w * v.w);
      *(u16x4*)(wob + i) = o;
    }
  } else if (bid < 20480) {  // LN(latents)
    const int row = bid - 4096;
    ln_row_f32(lat + (size_t)row * 1024, g_l, b_l, lnl + (size_t)row * 1024, tid, red);
  } else {  // LN(x)
    const int row = bid - 20480;
    ln_row_f32(x + (size_t)row * 1024, g_x, b_x, lnx + (size_t)row * 1024, tid, red);
  }
}

// ---------------- stats: ao row mean/rstd (bid<16384) + u/w vectors (bid>=16384) ----------------
__global__ __launch_bounds__(256) void stats_kernel(const u16* __restrict__ ao,
                                                    float* __restrict__ meanb,
                                                    float* __restrict__ rstdb,
                                                    const float* __restrict__ Wo,
                                                    const float* __restrict__ g_out,
                                                    const float* __restrict__ b_out,
                                                    float* __restrict__ ub,
                                                    float* __restrict__ wb) {
  __shared__ float red[8];
  const int bid = blockIdx.x, tid = threadIdx.x;
  if (bid < 16384) {  // row stats of ao
    const u16x4 r = *((const u16x4*)(ao + (size_t)bid * 1024) + tid);
    float v0 = bf2f(r[0]), v1 = bf2f(r[1]), v2 = bf2f(r[2]), v3 = bf2f(r[3]);
    float s = v0 + v1 + v2 + v3;
    float q = v0*v0 + v1*v1 + v2*v2 + v3*v3;
#pragma unroll
    for (int off = 32; off; off >>= 1) {
      s += __shfl_xor(s, off, 64);
      q += __shfl_xor(q, off, 64);
    }
    if ((tid & 63) == 0) { red[(tid >> 6) * 2] = s; red[(tid >> 6) * 2 + 1] = q; }
    __syncthreads();
    if (tid == 0) {
      s = red[0] + red[2] + red[4] + red[6];
      q = red[1] + red[3] + red[5] + red[7];
      const float m = s * (1.f / 1024.f);
      meanb[bid] = m;
      rstdb[bid] = rsqrtf(q * (1.f / 1024.f) - m * m + 1e-5f);
    }
  } else {  // u[c] = sum g_out[k]*Wo[c,k]; w[c] = sum b_out[k]*Wo[c,k]
    const int c = bid - 16384;
    const float4 v = *((const float4*)(Wo + (size_t)c * 1024) + tid);
    const float4 gv = *((const float4*)g_out + tid);
    const float4 bv = *((const float4*)b_out + tid);
    float su = gv.x*v.x + gv.y*v.y + gv.z*v.z + gv.w*v.w;
    float sw = bv.x*v.x + bv.y*v.y + bv.z*v.z + bv.w*v.w;
#pragma unroll
    for (int off = 32; off; off >>= 1) {
      su += __shfl_xor(su, off, 64);
      sw += __shfl_xor(sw, off, 64);
    }
    if ((tid & 63) == 0) { red[(tid >> 6) * 2] = su; red[(tid >> 6) * 2 + 1] = sw; }
    __syncthreads();
    if (tid == 0) {
      ub[c] = red[0] + red[2] + red[4] + red[6];
      wb[c] = red[1] + red[3] + red[5] + red[7];
    }
  }
}

// ---------------- GEMM core (4-phase schedule, 32x32x16 MFMA) ----------------
// acc[mb][nb]: mb in 0..3 (32-row blocks of the wave's 128 rows), nb in 0..1.
DEV void gemm_core32(const u16* __restrict__ Asrc, const u16* __restrict__ Bsrc,
                     u16 (&As)[2][16384], u16 (&Bs)[2][16384],
                     const int (&goff)[4], const int (&loff)[4], const int (&chk)[4],
                     int wm, int wn, int cl32, f32x16 (&acc)[4][2]) {
  constexpr int NT = 16;  // K-tiles of BK=64

#define STG_A(buf, kt, h) { gl16(Asrc + (size_t)(kt) * 64 + goff[2*(h)],     &As[buf][loff[2*(h)]]); \
                            gl16(Asrc + (size_t)(kt) * 64 + goff[2*(h)+1],   &As[buf][loff[2*(h)+1]]); }
#define STG_B(buf, kt, h) { gl16(Bsrc + (size_t)(kt) * 64 + goff[2*(h)],     &Bs[buf][loff[2*(h)]]); \
                            gl16(Bsrc + (size_t)(kt) * 64 + goff[2*(h)+1],   &Bs[buf][loff[2*(h)+1]]); }
#define LDA(H) _Pragma("unroll") for (int mp = 0; mp < 2; ++mp) \
               _Pragma("unroll") for (int ks = 0; ks < 4; ++ks) \
                 af[mp][ks] = *(const bf16x8*)&Ab[(wm * 128 + ((H)*2 + mp) * 32 + cl32) * 64 + chk[ks]];
#define LDB(DST, G) _Pragma("unroll") for (int ks = 0; ks < 4; ++ks) \
                      DST[ks] = *(const bf16x8*)&Bb[(wn * 64 + (G) * 32 + cl32) * 64 + chk[ks]];
#define MFMA_Q(H, BF, G) _Pragma("unroll") for (int ks = 0; ks < 4; ++ks) \
                         _Pragma("unroll") for (int mp = 0; mp < 2; ++mp) \
                           acc[(H)*2 + mp][G] = mfma32(af[mp][ks], BF[ks], acc[(H)*2 + mp][G]);

  // prologue: tile0 (A+B) into buf0, tile1 A-halves into buf1 (12 loads); wait oldest 8.
  STG_A(0, 0, 0); STG_A(0, 0, 1);
  STG_B(0, 0, 0); STG_B(0, 0, 1);
  STG_A(1, 1, 0); STG_A(1, 1, 1);
  asm volatile("s_waitcnt vmcnt(4)" ::: "memory");
  __builtin_amdgcn_s_barrier();

  for (int t = 0; t < NT; ++t) {
    const int bsel = t & 1;
    const u16* Ab = As[bsel];
    const u16* Bb = Bs[bsel];
    bf16x8 af[2][4], bfrA[4], bfrB[4];
    // ---- P0: (mh0, nb0); stage B-half0 of t+1 ----
    LDA(0); LDB(bfrA, 0);
    if (t + 1 < NT) STG_B(bsel ^ 1, t + 1, 0);
    __builtin_amdgcn_s_barrier();
    asm volatile("s_waitcnt lgkmcnt(0)" ::: "memory");
    __builtin_amdgcn_s_setprio(1);
    MFMA_Q(0, bfrA, 0);
    __builtin_amdgcn_s_setprio(0);
    __builtin_amdgcn_s_barrier();
    // ---- P1: (mh0, nb1); stage B-half1 of t+1 ----
    LDB(bfrB, 1);
    if (t + 1 < NT) STG_B(bsel ^ 1, t + 1, 1);
    __builtin_amdgcn_s_barrier();
    asm volatile("s_waitcnt lgkmcnt(0)" ::: "memory");
    __builtin_amdgcn_s_setprio(1);
    MFMA_Q(0, bfrB, 1);
    __builtin_amdgcn_s_setprio(0);
    __builtin_amdgcn_s_barrier();
    // ---- P2: (mh1, nb1)  (bfrB held) ----
    LDA(1);
    __builtin_amdgcn_s_barrier();
    asm volatile("s_waitcnt lgkmcnt(0)" ::: "memory");
    __builtin_amdgcn_s_setprio(1);
    MFMA_Q(1, bfrB, 1);
    __builtin_amdgcn_s_setprio(0);
    __builtin_amdgcn_s_barrier();
    // ---- P3: (mh1, nb0) — no reads (bfrA held); stage A of t+2; counted vmcnt ----
    if (t + 2 < NT) { STG_A(bsel, t + 2, 0); STG_A(bsel, t + 2, 1); }
    __builtin_amdgcn_s_setprio(1);
    MFMA_Q(1, bfrA, 0);
    __builtin_amdgcn_s_setprio(0);
    if (t + 2 < NT) asm volatile("s_waitcnt vmcnt(4)" ::: "memory");
    else            asm volatile("s_waitcnt vmcnt(0)" ::: "memory");
    __builtin_amdgcn_s_barrier();
  }
#undef STG_A
#undef STG_B
#undef LDA
#undef LDB
#undef MFMA_Q
}

DEV void gemm_prep32(int tid, int lane, int (&goff)[4], int (&loff)[4], int (&chk)[4],
                     f32x16 (&acc)[4][2]) {
  // staging: slot s = i*512+tid covers (row = s>>3, phys-chunk = s&7).
  // LDS stays linear (gload_lds requirement); global source pre-inverse-swizzled.
#pragma unroll
  for (int i = 0; i < 4; ++i) {
    const int s = i * 512 + tid;
    const int gr = s >> 3, gc = (s & 7) ^ (gr & 7);
    goff[i] = gr * 1024 + gc * 8;
    loff[i] = s * 8;
  }
  // frag reads: logical chunk = ks*2 + (lane>>5); phys = logical ^ (row&7), row&7 == lane&7
  const int s5 = lane >> 5;
#pragma unroll
  for (int ks = 0; ks < 4; ++ks) chk[ks] = (((ks << 1) + s5) ^ (lane & 7)) * 8;
#pragma unroll
  for (int m = 0; m < 4; ++m)
#pragma unroll
    for (int n = 0; n < 2; ++n)
#pragma unroll
      for (int e = 0; e < 16; ++e) acc[m][n][e] = 0.f;
}

// ---------------- merged QKV GEMM ----------------
// logical wg < 2048: lnx(65536xK) @ Bkv[tn] -> tn<4: K (b,h,t,d); tn>=4: V^T (b,h,d,t)
// logical wg >= 2048: lnl(16384xK) @ Wq[tn] -> Q (b,h,i,d); tiles_n=4
__global__ __launch_bounds__(512, 2) void gemm_qkv(const u16* __restrict__ A0,
                                                   const u16* __restrict__ A1,
                                                   const u16* __restrict__ Bkv,
                                                   const u16* __restrict__ Bq,
                                                   u16* __restrict__ kb,
                                                   u16* __restrict__ vt,
                                                   u16* __restrict__ qb) {
  __shared__ u16 As[2][16384];
  __shared__ u16 Bs[2][16384];
  const int tid = threadIdx.x, lane = tid & 63, wid = tid >> 6;
  const int wm = wid >> 2, wn = wid & 3;
  // bijective chunked XCD swizzle (gridDim 2304 divisible by 8: q8=288)
  const int q8 = (int)gridDim.x >> 3;
  const int wg = ((int)blockIdx.x & 7) * q8 + ((int)blockIdx.x >> 3);
  const bool isQ = wg >= 2048;
  const int wg0 = isQ ? wg - 2048 : wg;
  const int tiles_n = isQ ? 4 : 8;
  const int tn = wg0 % tiles_n, tm = wg0 / tiles_n;

  const u16* Asrc = (isQ ? A1 : A0) + (size_t)tm * 262144;
  const u16* Bsrc = (isQ ? Bq : Bkv) + (size_t)tn * 262144;

  const int cl32 = lane & 31, s5 = lane >> 5;
  int goff[4], loff[4], chk[4];
  f32x16 acc[4][2];
  gemm_prep32(tid, lane, goff, loff, chk, acc);
  gemm_core32(Asrc, Bsrc, As, Bs, goff, loff, chk, wm, wn, cl32, acc);

  // epilogue. C/D: col = cl32, row = (reg&3) + 8*(reg>>2) + 4*s5 within 32x32.
  if (isQ) {  // Q: (b,h,i,d)
#pragma unroll
    for (int mb = 0; mb < 4; ++mb) {
      const int rb = tm * 256 + wm * 128 + mb * 32 + s5 * 4;
#pragma unroll
      for (int nb = 0; nb < 2; ++nb) {
        const int c = tn * 256 + wn * 64 + nb * 32 + cl32;
        const int h = c >> 6, d = c & 63;
        const f32x16 a = acc[mb][nb];
#pragma unroll
        for (int q = 0; q < 4; ++q)
#pragma unroll
          for (int j = 0; j < 4; ++j) {
            const int r = rb + q * 8 + j;
            const int b = r >> 6, i0 = r & 63;
            qb[((size_t)(b * 16 + h) * 64 + i0) * 64 + d] = f2bf(a[q * 4 + j]);
          }
      }
    }
  } else if (tn < 4) {  // K half: (b,h,t,d), b == tm
#pragma unroll
    for (int mb = 0; mb < 4; ++mb) {
      const int tb = wm * 128 + mb * 32 + s5 * 4;
#pragma unroll
      for (int nb = 0; nb < 2; ++nb) {
        const int c = tn * 256 + wn * 64 + nb * 32 + cl32;
        const int h = c >> 6, d = c & 63;
        const f32x16 a = acc[mb][nb];
#pragma unroll
        for (int q = 0; q < 4; ++q)
#pragma unroll
          for (int j = 0; j < 4; ++j) {
            const int t = tb + q * 8 + j;
            kb[((size_t)(tm * 16 + h) * 256 + t) * 64 + d] = f2bf(a[q * 4 + j]);
          }
      }
    }
  } else {  // V half, transposed: (b,h,d,t) — 4 consecutive t per reg-quad
#pragma unroll
    for (int mb = 0; mb < 4; ++mb) {
      const int tb = wm * 128 + mb * 32 + s5 * 4;
#pragma unroll
      for (int nb = 0; nb < 2; ++nb) {
        const int c = (tn - 4) * 256 + wn * 64 + nb * 32 + cl32;
        const int h = c >> 6, d = c & 63;
        const f32x16 a = acc[mb][nb];
#pragma unroll
        for (int q = 0; q < 4; ++q) {
          u16x4 o;
#pragma unroll
          for (int j = 0; j < 4; ++j) o[j] = f2bf(a[q * 4 + j]);
          *(u16x4*)(vt + ((size_t)(tm * 16 + h) * 64 + d) * 256 + tb + q * 8) = o;
        }
      }
    }
  }
}

// ---------------- output GEMM: raw ao @ wob^T with LN-commuted epilogue ----------------
__global__ __launch_bounds__(512, 2) void gemm_out(const u16* __restrict__ A,
                                                   const u16* __restrict__ Bo,
                                                   const float* __restrict__ ub,
                                                   const float* __restrict__ wb,
                                                   const float* __restrict__ bias,
                                                   const float* __restrict__ meanb,
                                                   const float* __restrict__ rstdb,
                                                   const float* __restrict__ resid,
                                                   float* __restrict__ outf) {
  __shared__ u16 As[2][16384];
  __shared__ u16 Bs[2][16384];
  const int tid = threadIdx.x, lane = tid & 63, wid = tid >> 6;
  const int wm = wid >> 2, wn = wid & 3;
  const int q8 = (int)gridDim.x >> 3;
  const int wg = ((int)blockIdx.x & 7) * q8 + ((int)blockIdx.x >> 3);
  const int tn = wg % 4, tm = wg / 4;

  const u16* Asrc = A + (size_t)tm * 262144;
  const u16* Bsrc = Bo + (size_t)tn * 262144;

  const int cl32 = lane & 31, s5 = lane >> 5;
  int goff[4], loff[4], chk[4];
  f32x16 acc[4][2];
  gemm_prep32(tid, lane, goff, loff, chk, acc);
  gemm_core32(Asrc, Bsrc, As, Bs, goff, loff, chk, wm, wn, cl32, acc);

  // out[r,c] = rstd[r]*acc - rstd[r]*mean[r]*u[c] + w[c] + bias[c] + resid[r,c]
#pragma unroll
  for (int mb = 0; mb < 4; ++mb) {
    const int rb = tm * 256 + wm * 128 + mb * 32 + s5 * 4;
#pragma unroll
    for (int nb = 0; nb < 2; ++nb) {
      const int c = tn * 256 + wn * 64 + nb * 32 + cl32;
      const float uc = ub[c];
      const float wc = wb[c] + bias[c];
      const f32x16 a = acc[mb][nb];
#pragma unroll
      for (int q = 0; q < 4; ++q)
#pragma unroll
        for (int j = 0; j < 4; ++j) {
          const int r = rb + q * 8 + j;
          const float rs = rstdb[r], mn = meanb[r];
          const size_t idx = (size_t)r * 1024 + c;
          outf[idx] = rs * a[q * 4 + j] - rs * mn * uc + wc + resid[idx];
        }
    }
  }
}

// ---------------- attention: one block per (b,h); 4 waves, each owns 16 q-rows ----------------
__global__ __launch_bounds__(256) void attn_kernel(const u16* __restrict__ Qb,
                                                   const u16* __restrict__ Kb,
                                                   const u16* __restrict__ Vt,
                                                   u16* __restrict__ AO) {
  __shared__ u16 Qs[64 * 64];    // 8 KB  (i,d)
  __shared__ u16 Ks[256 * 64];   // 32 KB (t,d), reused as P (i,t) later
  __shared__ u16 Vs[64 * 256];   // 32 KB (d,t)
  const int bh = blockIdx.x;
  const int tid = threadIdx.x, lane = tid & 63, wv = tid >> 6;
  const u16* qsrc = Qb + (size_t)bh * 4096;
  const u16* ksrc = Kb + (size_t)bh * 16384;
  const u16* vsrc = Vt + (size_t)bh * 16384;
  // stage Q,K first; V issued but NOT waited before QK^T (overlap)
#pragma unroll
  for (int i = 0; i < 2; ++i) gl16(qsrc + (i * 256 + tid) * 8, &Qs[(i * 256 + tid) * 8]);
#pragma unroll
  for (int i = 0; i < 8; ++i) gl16(ksrc + (i * 256 + tid) * 8, &Ks[(i * 256 + tid) * 8]);
#pragma unroll
  for (int i = 0; i < 8; ++i) gl16(vsrc + (i * 256 + tid) * 8, &Vs[(i * 256 + tid) * 8]);
  asm volatile("s_waitcnt vmcnt(8)" ::: "memory");  // Q+K resident; V (8) in flight
  __builtin_amdgcn_s_barrier();

  f32x4 sacc[16];
  const f32x4 z = {0.f, 0.f, 0.f, 0.f};
#pragma unroll
  for (int n = 0; n < 16; ++n) sacc[n] = z;
#pragma unroll
  for (int s = 0; s < 2; ++s) {
    const bf16x8 aq = *(const bf16x8*)&Qs[(wv * 16 + (lane & 15)) * 64 + s * 32 + (lane >> 4) * 8];
#pragma unroll
    for (int n = 0; n < 16; ++n) {
      const bf16x8 bk = *(const bf16x8*)&Ks[(n * 16 + (lane & 15)) * 64 + s * 32 + (lane >> 4) * 8];
      sacc[n] = mfma16(aq, bk, sacc[n]);
    }
  }

  // mask + softmax; keep P unnormalized, fold 1/sum into O-write
  const int rgrp = lane >> 4, cl = lane & 15;
  float inv[4];
#pragma unroll
  for (int j = 0; j < 4; ++j) {
    const int qrow = (wv << 4) + (rgrp << 2) + j;
    float m_ = -1e30f;
#pragma unroll
    for (int n = 0; n < 16; ++n) {
      const int col = (n << 4) + cl;
      float sv = sacc[n][j] * 0.125f;
      sv = ((col >> 2) <= qrow) ? sv : -1e30f;
      sacc[n][j] = sv;
      m_ = fmaxf(m_, sv);
    }
#pragma unroll
    for (int off = 8; off; off >>= 1) m_ = fmaxf(m_, __shfl_xor(m_, off, 64));
    float s_ = 0.f;
#pragma unroll
    for (int n = 0; n < 16; ++n) {
      const float p = exp2f((sacc[n][j] - m_) * 1.44269504f);
      sacc[n][j] = p;
      s_ += p;
    }
#pragma unroll
    for (int off = 8; off; off >>= 1) s_ += __shfl_xor(s_, off, 64);
    inv[j] = 1.0f / s_;
  }

  asm volatile("s_waitcnt vmcnt(0)" ::: "memory");  // V resident
  __builtin_amdgcn_s_barrier();                     // all waves past QK reads of Ks
  u16* Ps = Ks;                                     // reuse as P~ (i,t) row-major
#pragma unroll
  for (int n = 0; n < 16; ++n)
#pragma unroll
    for (int j = 0; j < 4; ++j)
      Ps[((wv << 4) + (rgrp << 2) + j) * 256 + (n << 4) + cl] = f2bf(sacc[n][j]);
  __syncthreads();

  f32x4 oacc[4];
#pragma unroll
  for (int n = 0; n < 4; ++n) oacc[n] = z;
#pragma unroll
  for (int ks = 0; ks < 8; ++ks) {
    const bf16x8 ap = *(const bf16x8*)&Ps[(wv * 16 + (lane & 15)) * 256 + ks * 32 + (lane >> 4) * 8];
#pragma unroll
    for (int n = 0; n < 4; ++n) {
      const bf16x8 bv = *(const bf16x8*)&Vs[(n * 16 + (lane & 15)) * 256 + ks * 32 + (lane >> 4) * 8];
      oacc[n] = mfma16(ap, bv, oacc[n]);
    }
  }
  const int b = bh >> 4, h = bh & 15;
  u16* obase = AO + (size_t)b * 65536 + (size_t)h * 64;
#pragma unroll
  for (int n = 0; n < 4; ++n)
#pragma unroll
    for (int j = 0; j < 4; ++j) {
      const int qrow = (wv << 4) + (rgrp << 2) + j;
      const int d = (n << 4) + cl;
      obase[(size_t)qrow * 1024 + d] = f2bf(oacc[n][j] * inv[j]);
    }
}

// ---------------- launch ----------------
extern "C" void kernel_launch(void* const* d_in, const int* in_sizes, int n_in,
                              void* d_out, int out_size, void* d_ws, size_t ws_size,
                              hipStream_t stream) {
  const float* x     = (const float*)d_in[0];
  const float* lat   = (const float*)d_in[1];
  const float* Wq    = (const float*)d_in[2];
  const float* Wk    = (const float*)d_in[3];
  const float* Wv    = (const float*)d_in[4];
  const float* Wo    = (const float*)d_in[5];
  const float* bo    = (const float*)d_in[6];
  const float* g_out = (const float*)d_in[7];
  const float* b_out = (const float*)d_in[8];
  const float* g_x   = (const float*)d_in[9];
  const float* b_x   = (const float*)d_in[10];
  const float* g_l   = (const float*)d_in[11];
  const float* b_l   = (const float*)d_in[12];
  float* out = (float*)d_out;

  char* W = (char*)d_ws;
  u16* wqb = (u16*)(W + 0);            // 2 MiB each, contiguous
  u16* wkb = (u16*)(W + 2097152);
  u16* wvb = (u16*)(W + 4194304);      // contiguous after wkb (merged B indexing)
  u16* wob = (u16*)(W + 6291456);      // bf16(g_out ⊙ Wo)
  u16* lnl = (u16*)(W + 8388608);      // 32 MiB
  u16* lnx = (u16*)(W + 41943040);     // 128 MiB
  u16* qb  = (u16*)(W + 176160768);    // 32 MiB
  u16* kb  = (u16*)(W + 209715200);    // 128 MiB
  u16* vt  = (u16*)(W + 343932928);    // 128 MiB
  u16* ao  = lnx;                      // alias: lnx dead after gemm_qkv
  // qb dead after attn: reuse for stats outputs
  float* meanb = (float*)qb;                       // 64 KiB
  float* rstdb = (float*)((char*)qb + 65536);      // 64 KiB
  float* ub    = (float*)((char*)qb + 131072);     // 4 KiB
  float* wb    = (float*)((char*)qb + 135168);     // 4 KiB
  (void)wvb;

  fused_pre<<<86016, 256, 0, stream>>>(Wq, Wk, Wv, Wo, wqb, wob, g_out,
                                       lat, g_l, b_l, lnl,
                                       x, g_x, b_x, lnx);

  gemm_qkv<<<2304, 512, 0, stream>>>(lnx, lnl, wkb, wqb, kb, vt, qb);

  attn_kernel<<<4096, 256, 0, stream>>>(qb, kb, vt, ao);

  stats_kernel<<<17408, 256, 0, stream>>>(ao, meanb, rstdb, Wo, g_out, b_out, ub, wb);

  gemm_out<<<256, 512, 0, stream>>>(ao, wob, ub, wb, bo, meanb, rstdb, lat, out);
}

// Round 9
// 619.972 us; speedup vs baseline: 1.0454x; 1.0454x over previous
//
#include <hip/hip_runtime.h>

// B=256, DIM=1024, H=16, HD=64, DS=4, NL=64, NKV=256
// Pipeline (5 launches):
//  1. fused_pre: Wq/Wk/Wv->bf16, wob = bf16(g_out⊙Wo), LN(latents)->lnl, LN(x)->lnx
//  2. gemm_qkv: merged [lnx @ [Wk;Wv]^T -> K,(V^T)] + [lnl @ Wq^T -> Q]
//  3. attn per (b,h): S=Q K^T*0.125, mask (col>>2)<=row, softmax, O=P~ V -> ao
//  4. stats: row mean/rstd of ao  +  u[c]=Σ g_out·Wo[c,:], w[c]=Σ b_out·Wo[c,:]
//  5. gemm_out: raw ao @ wob^T, epilogue out = rstd*acc - rstd*mean*u + w + bo + resid
//     (LN commuted through the GEMM: LN(a)@Wo^T = rstd*(a@(g⊙Wo)^T) - rstd*mean*u + w)
//
// GEMM core: R7-proven 16x16x32 MFMA, 256x256 tile, BK=64, 8 waves (2Mx4N),
// 128KiB dbuf LDS, 4-phase double-barrier schedule, counted vmcnt(4), chunk-XOR
// swizzle, setprio, bijective chunked XCD swizzle. ~900 TF @ K=1024.
// REJECTED levers (do not retry):
//  - fp8 QKV GEMM (R6): absmax 0.37 > 0.149, fundamental e4m3 mantissa limit.
//  - 32x32x16 MFMA (R8): correct but ds_read pattern conflicts with the XOR
//    swizzle (2.8e7 bank conflicts), gemm_qkv 374->403 us.
//  - 8-phase (R2) and 1-barrier (R4) schedules: both ~31% MfmaUtil vs 35%.

typedef unsigned short u16;
typedef float f32x4 __attribute__((ext_vector_type(4)));
typedef short bf16x8 __attribute__((ext_vector_type(8)));
typedef u16 u16x4 __attribute__((ext_vector_type(4)));

#define DEV __device__ __forceinline__

DEV u16 f2bf(float f) {
  union { float f; unsigned int u; } c; c.f = f;
  unsigned int u = c.u;
  u += 0x7fffu + ((u >> 16) & 1u);   // RNE
  return (u16)(u >> 16);
}
DEV float bf2f(u16 u) {
  union { unsigned int u; float f; } c; c.u = ((unsigned int)u) << 16; return c.f;
}
DEV f32x4 mfma16(bf16x8 a, bf16x8 b, f32x4 c) {
  return __builtin_amdgcn_mfma_f32_16x16x32_bf16(a, b, c, 0, 0, 0);
}
DEV void gl16(const void* g, void* l) {
  __builtin_amdgcn_global_load_lds((const __attribute__((address_space(1))) void*)g,
                                   (__attribute__((address_space(3))) void*)l, 16, 0, 0);
}

// ---------------- LN row helper: 1024 elems, 256 threads ----------------
DEV void ln_row_f32(const float* __restrict__ srcrow, const float* __restrict__ g,
                    const float* __restrict__ bta, u16* __restrict__ dstrow,
                    int tid, float* red) {
  const float4 r = *((const float4*)srcrow + tid);
  float v[4] = {r.x, r.y, r.z, r.w};
  float s = v[0] + v[1] + v[2] + v[3];
  float q = v[0]*v[0] + v[1]*v[1] + v[2]*v[2] + v[3]*v[3];
#pragma unroll
  for (int off = 32; off; off >>= 1) {
    s += __shfl_xor(s, off, 64);
    q += __shfl_xor(q, off, 64);
  }
  if ((tid & 63) == 0) { red[(tid >> 6) * 2] = s; red[(tid >> 6) * 2 + 1] = q; }
  __syncthreads();
  s = red[0] + red[2] + red[4] + red[6];
  q = red[1] + red[3] + red[5] + red[7];
  const float mean = s * (1.f / 1024.f);
  const float rstd = rsqrtf(q * (1.f / 1024.f) - mean * mean + 1e-5f);
  const float4 gv = *((const float4*)g + tid);
  const float4 bv = *((const float4*)bta + tid);
  u16x4 o;
  o[0] = f2bf((v[0] - mean) * rstd * gv.x + bv.x);
  o[1] = f2bf((v[1] - mean) * rstd * gv.y + bv.y);
  o[2] = f2bf((v[2] - mean) * rstd * gv.z + bv.z);
  o[3] = f2bf((v[3] - mean) * rstd * gv.w + bv.w);
  *((u16x4*)dstrow + tid) = o;
}

// ---------------- fused: weight cvt + LN(latents) + LN(x) ----------------
// g<3: Wq/Wk/Wv -> bf16 at wout + g*1M. g==3: wob = bf16(g_out[k]*Wo[c,k]).
__global__ __launch_bounds__(256) void fused_pre(const float* __restrict__ w0,
                                                 const float* __restrict__ w1,
                                                 const float* __restrict__ w2,
                                                 const float* __restrict__ w3,
                                                 u16* __restrict__ wout,
                                                 u16* __restrict__ wob,
                                                 const float* __restrict__ g_out,
                                                 const float* __restrict__ lat,
                                                 const float* __restrict__ g_l,
                                                 const float* __restrict__ b_l,
                                                 u16* __restrict__ lnl,
                                                 const float* __restrict__ x,
                                                 const float* __restrict__ g_x,
                                                 const float* __restrict__ b_x,
                                                 u16* __restrict__ lnx) {
  __shared__ float red[8];
  const int bid = blockIdx.x, tid = threadIdx.x;
  if (bid < 4096) {  // weight convert
    const int g = bid >> 10;
    const int i = ((bid & 1023) * 256 + tid) * 4;
    if (g < 3) {
      const float* src = (g == 0) ? w0 : (g == 1) ? w1 : w2;
      const float4 v = *(const float4*)(src + i);
      u16x4 o; o[0] = f2bf(v.x); o[1] = f2bf(v.y); o[2] = f2bf(v.z); o[3] = f2bf(v.w);
      *(u16x4*)(wout + (size_t)g * 1048576 + i) = o;
    } else {  // row c = bid&1023 of Wo; fold g_out into the weight
      const float4 v = *(const float4*)(w3 + i);
      const float4 gv = *((const float4*)g_out + tid);
      u16x4 o;
      o[0] = f2bf(gv.x * v.x); o[1] = f2bf(gv.y * v.y);
      o[2] = f2bf(gv.z * v.z); o[3] = f2bf(gv.w * v.w);
      *(u16x4*)(wob + i) = o;
    }
  } else if (bid < 20480) {  // LN(latents)
    const int row = bid - 4096;
    ln_row_f32(lat + (size_t)row * 1024, g_l, b_l, lnl + (size_t)row * 1024, tid, red);
  } else {  // LN(x)
    const int row = bid - 20480;
    ln_row_f32(x + (size_t)row * 1024, g_x, b_x, lnx + (size_t)row * 1024, tid, red);
  }
}

// ---------------- stats: ao row mean/rstd (bid<16384) + u/w vectors (bid>=16384) ----------------
__global__ __launch_bounds__(256) void stats_kernel(const u16* __restrict__ ao,
                                                    float* __restrict__ meanb,
                                                    float* __restrict__ rstdb,
                                                    const float* __restrict__ Wo,
                                                    const float* __restrict__ g_out,
                                                    const float* __restrict__ b_out,
                                                    float* __restrict__ ub,
                                                    float* __restrict__ wb) {
  __shared__ float red[8];
  const int bid = blockIdx.x, tid = threadIdx.x;
  if (bid < 16384) {  // row stats of ao
    const u16x4 r = *((const u16x4*)(ao + (size_t)bid * 1024) + tid);
    float v0 = bf2f(r[0]), v1 = bf2f(r[1]), v2 = bf2f(r[2]), v3 = bf2f(r[3]);
    float s = v0 + v1 + v2 + v3;
    float q = v0*v0 + v1*v1 + v2*v2 + v3*v3;
#pragma unroll
    for (int off = 32; off; off >>= 1) {
      s += __shfl_xor(s, off, 64);
      q += __shfl_xor(q, off, 64);
    }
    if ((tid & 63) == 0) { red[(tid >> 6) * 2] = s; red[(tid >> 6) * 2 + 1] = q; }
    __syncthreads();
    if (tid == 0) {
      s = red[0] + red[2] + red[4] + red[6];
      q = red[1] + red[3] + red[5] + red[7];
      const float m = s * (1.f / 1024.f);
      meanb[bid] = m;
      rstdb[bid] = rsqrtf(q * (1.f / 1024.f) - m * m + 1e-5f);
    }
  } else {  // u[c] = sum g_out[k]*Wo[c,k]; w[c] = sum b_out[k]*Wo[c,k]
    const int c = bid - 16384;
    const float4 v = *((const float4*)(Wo + (size_t)c * 1024) + tid);
    const float4 gv = *((const float4*)g_out + tid);
    const float4 bv = *((const float4*)b_out + tid);
    float su = gv.x*v.x + gv.y*v.y + gv.z*v.z + gv.w*v.w;
    float sw = bv.x*v.x + bv.y*v.y + bv.z*v.z + bv.w*v.w;
#pragma unroll
    for (int off = 32; off; off >>= 1) {
      su += __shfl_xor(su, off, 64);
      sw += __shfl_xor(sw, off, 64);
    }
    if ((tid & 63) == 0) { red[(tid >> 6) * 2] = su; red[(tid >> 6) * 2 + 1] = sw; }
    __syncthreads();
    if (tid == 0) {
      ub[c] = red[0] + red[2] + red[4] + red[6];
      wb[c] = red[1] + red[3] + red[5] + red[7];
    }
  }
}

// ---------------- GEMM core (R7 16x16x32, 4-phase schedule) ----------------
DEV void gemm_core(const u16* __restrict__ Asrc, const u16* __restrict__ Bsrc,
                   u16 (&As)[2][16384], u16 (&Bs)[2][16384],
                   const int (&goff)[4], const int (&loff)[4], const int (&chk)[2],
                   int wm, int wn, int fr, f32x4 (&acc)[8][4]) {
  constexpr int NT = 16;  // K-tiles of BK=64

#define STG_A(buf, kt, h) { gl16(Asrc + (size_t)(kt) * 64 + goff[2*(h)],     &As[buf][loff[2*(h)]]); \
                            gl16(Asrc + (size_t)(kt) * 64 + goff[2*(h)+1],   &As[buf][loff[2*(h)+1]]); }
#define STG_B(buf, kt, h) { gl16(Bsrc + (size_t)(kt) * 64 + goff[2*(h)],     &Bs[buf][loff[2*(h)]]); \
                            gl16(Bsrc + (size_t)(kt) * 64 + goff[2*(h)+1],   &Bs[buf][loff[2*(h)+1]]); }
#define LDA(H) _Pragma("unroll") for (int mp = 0; mp < 4; ++mp) \
               _Pragma("unroll") for (int ks = 0; ks < 2; ++ks) \
                 af[mp][ks] = *(const bf16x8*)&Ab[(wm * 128 + ((H)*4 + mp) * 16 + fr) * 64 + chk[ks]];
#define LDB(DST, G) _Pragma("unroll") for (int np = 0; np < 2; ++np) \
                    _Pragma("unroll") for (int ks = 0; ks < 2; ++ks) \
                      DST[np][ks] = *(const bf16x8*)&Bb[(wn * 64 + ((G)*2 + np) * 16 + fr) * 64 + chk[ks]];
#define MFMA_Q(H, BF, G) _Pragma("unroll") for (int mp = 0; mp < 4; ++mp) \
                         _Pragma("unroll") for (int np = 0; np < 2; ++np) \
                         _Pragma("unroll") for (int ks = 0; ks < 2; ++ks) \
                           acc[(H)*4 + mp][(G)*2 + np] = mfma16(af[mp][ks], BF[np][ks], acc[(H)*4 + mp][(G)*2 + np]);

  // prologue: tile0 (A+B) into buf0, tile1 A-halves into buf1 (12 loads); wait oldest 8.
  STG_A(0, 0, 0); STG_A(0, 0, 1);
  STG_B(0, 0, 0); STG_B(0, 0, 1);
  STG_A(1, 1, 0); STG_A(1, 1, 1);
  asm volatile("s_waitcnt vmcnt(4)" ::: "memory");
  __builtin_amdgcn_s_barrier();

  for (int t = 0; t < NT; ++t) {
    const int bsel = t & 1;
    const u16* Ab = As[bsel];
    const u16* Bb = Bs[bsel];
    bf16x8 af[4][2], bfrA[2][2], bfrB[2][2];
    // ---- P0: (mh0, ng0); stage B-half0 of t+1 ----
    LDA(0); LDB(bfrA, 0);
    if (t + 1 < NT) STG_B(bsel ^ 1, t + 1, 0);
    __builtin_amdgcn_s_barrier();
    asm volatile("s_waitcnt lgkmcnt(0)" ::: "memory");
    __builtin_amdgcn_s_setprio(1);
    MFMA_Q(0, bfrA, 0);
    __builtin_amdgcn_s_setprio(0);
    __builtin_amdgcn_s_barrier();
    // ---- P1: (mh0, ng1); stage B-half1 of t+1 ----
    LDB(bfrB, 1);
    if (t + 1 < NT) STG_B(bsel ^ 1, t + 1, 1);
    __builtin_amdgcn_s_barrier();
    asm volatile("s_waitcnt lgkmcnt(0)" ::: "memory");
    __builtin_amdgcn_s_setprio(1);
    MFMA_Q(0, bfrB, 1);
    __builtin_amdgcn_s_setprio(0);
    __builtin_amdgcn_s_barrier();
    // ---- P2: (mh1, ng1)  (bfrB held) ----
    LDA(1);
    __builtin_amdgcn_s_barrier();
    asm volatile("s_waitcnt lgkmcnt(0)" ::: "memory");
    __builtin_amdgcn_s_setprio(1);
    MFMA_Q(1, bfrB, 1);
    __builtin_amdgcn_s_setprio(0);
    __builtin_amdgcn_s_barrier();
    // ---- P3: (mh1, ng0) — no reads (bfrA held); stage A of t+2; counted vmcnt ----
    if (t + 2 < NT) { STG_A(bsel, t + 2, 0); STG_A(bsel, t + 2, 1); }
    __builtin_amdgcn_s_setprio(1);
    MFMA_Q(1, bfrA, 0);
    __builtin_amdgcn_s_setprio(0);
    if (t + 2 < NT) asm volatile("s_waitcnt vmcnt(4)" ::: "memory");
    else            asm volatile("s_waitcnt vmcnt(0)" ::: "memory");
    __builtin_amdgcn_s_barrier();
  }
#undef STG_A
#undef STG_B
#undef LDA
#undef LDB
#undef MFMA_Q
}

DEV void gemm_prep(int tid, int lane, int (&goff)[4], int (&loff)[4], int (&chk)[2],
                   f32x4 (&acc)[8][4]) {
  // staging: slot s = i*512+tid covers (row = s>>3, phys-chunk = s&7).
  // LDS stays linear (gload_lds requirement); global source pre-inverse-swizzled.
#pragma unroll
  for (int i = 0; i < 4; ++i) {
    const int s = i * 512 + tid;
    const int gr = s >> 3, gc = (s & 7) ^ (gr & 7);
    goff[i] = gr * 1024 + gc * 8;
    loff[i] = s * 8;
  }
  const int fq = lane >> 4;
#pragma unroll
  for (int ks = 0; ks < 2; ++ks) chk[ks] = ((((ks << 2) + fq)) ^ (lane & 7)) * 8;
  const f32x4 z = {0.f, 0.f, 0.f, 0.f};
#pragma unroll
  for (int m = 0; m < 8; ++m)
#pragma unroll
    for (int n = 0; n < 4; ++n) acc[m][n] = z;
}

// ---------------- merged QKV GEMM ----------------
// logical wg < 2048: lnx(65536xK) @ Bkv[tn] -> tn<4: K (b,h,t,d); tn>=4: V^T (b,h,d,t)
// logical wg >= 2048: lnl(16384xK) @ Wq[tn] -> Q (b,h,i,d); tiles_n=4
__global__ __launch_bounds__(512, 2) void gemm_qkv(const u16* __restrict__ A0,
                                                   const u16* __restrict__ A1,
                                                   const u16* __restrict__ Bkv,
                                                   const u16* __restrict__ Bq,
                                                   u16* __restrict__ kb,
                                                   u16* __restrict__ vt,
                                                   u16* __restrict__ qb) {
  __shared__ u16 As[2][16384];
  __shared__ u16 Bs[2][16384];
  const int tid = threadIdx.x, lane = tid & 63, wid = tid >> 6;
  const int wm = wid >> 2, wn = wid & 3;
  // bijective chunked XCD swizzle (gridDim 2304 divisible by 8: q8=288)
  const int q8 = (int)gridDim.x >> 3;
  const int wg = ((int)blockIdx.x & 7) * q8 + ((int)blockIdx.x >> 3);
  const bool isQ = wg >= 2048;
  const int wg0 = isQ ? wg - 2048 : wg;
  const int tiles_n = isQ ? 4 : 8;
  const int tn = wg0 % tiles_n, tm = wg0 / tiles_n;

  const u16* Asrc = (isQ ? A1 : A0) + (size_t)tm * 262144;
  const u16* Bsrc = (isQ ? Bq : Bkv) + (size_t)tn * 262144;

  int goff[4], loff[4], chk[2];
  f32x4 acc[8][4];
  gemm_prep(tid, lane, goff, loff, chk, acc);
  gemm_core(Asrc, Bsrc, As, Bs, goff, loff, chk, wm, wn, lane & 15, acc);

  // epilogue. C/D frag layout: row = fq*4 + j, col = fr within each 16x16.
  const int fr = lane & 15, fq = lane >> 4;
  if (isQ) {  // Q: (b,h,i,d)
#pragma unroll
    for (int m = 0; m < 8; ++m) {
      const int r0 = tm * 256 + wm * 128 + m * 16 + fq * 4;
      const int b = r0 >> 6, i0 = r0 & 63;
#pragma unroll
      for (int n = 0; n < 4; ++n) {
        const int c = tn * 256 + wn * 64 + n * 16 + fr;
        const int h = c >> 6, d = c & 63;
        u16* p = qb + ((size_t)(b * 16 + h) * 64 + i0) * 64 + d;
#pragma unroll
        for (int j = 0; j < 4; ++j) p[j * 64] = f2bf(acc[m][n][j]);
      }
    }
  } else if (tn < 4) {  // K half: (b,h,t,d), b == tm
#pragma unroll
    for (int m = 0; m < 8; ++m) {
      const int t0 = wm * 128 + m * 16 + fq * 4;
#pragma unroll
      for (int n = 0; n < 4; ++n) {
        const int c = tn * 256 + wn * 64 + n * 16 + fr;
        const int h = c >> 6, d = c & 63;
        u16* p = kb + ((size_t)(tm * 16 + h) * 256 + t0) * 64 + d;
#pragma unroll
        for (int j = 0; j < 4; ++j) p[j * 64] = f2bf(acc[m][n][j]);
      }
    }
  } else {  // V half, transposed: (b,h,d,t)
#pragma unroll
    for (int m = 0; m < 8; ++m) {
      const int t0 = wm * 128 + m * 16 + fq * 4;
#pragma unroll
      for (int n = 0; n < 4; ++n) {
        const int c = (tn - 4) * 256 + wn * 64 + n * 16 + fr;
        const int h = c >> 6, d = c & 63;
        u16x4 o;
#pragma unroll
        for (int j = 0; j < 4; ++j) o[j] = f2bf(acc[m][n][j]);
        *(u16x4*)(vt + ((size_t)(tm * 16 + h) * 64 + d) * 256 + t0) = o;
      }
    }
  }
}

// ---------------- output GEMM: raw ao @ wob^T with LN-commuted epilogue ----------------
__global__ __launch_bounds__(512, 2) void gemm_out(const u16* __restrict__ A,
                                                   const u16* __restrict__ Bo,
                                                   const float* __restrict__ ub,
                                                   const float* __restrict__ wb,
                                                   const float* __restrict__ bias,
                                                   const float* __restrict__ meanb,
                                                   const float* __restrict__ rstdb,
                                                   const float* __restrict__ resid,
                                                   float* __restrict__ outf) {
  __shared__ u16 As[2][16384];
  __shared__ u16 Bs[2][16384];
  const int tid = threadIdx.x, lane = tid & 63, wid = tid >> 6;
  const int wm = wid >> 2, wn = wid & 3;
  const int q8 = (int)gridDim.x >> 3;
  const int wg = ((int)blockIdx.x & 7) * q8 + ((int)blockIdx.x >> 3);
  const int tn = wg % 4, tm = wg / 4;

  const u16* Asrc = A + (size_t)tm * 262144;
  const u16* Bsrc = Bo + (size_t)tn * 262144;

  int goff[4], loff[4], chk[2];
  f32x4 acc[8][4];
  gemm_prep(tid, lane, goff, loff, chk, acc);
  gemm_core(Asrc, Bsrc, As, Bs, goff, loff, chk, wm, wn, lane & 15, acc);

  // out[r,c] = rstd[r]*acc - rstd[r]*mean[r]*u[c] + w[c] + bias[c] + resid[r,c]
  const int fr = lane & 15, fq = lane >> 4;
#pragma unroll
  for (int m = 0; m < 8; ++m) {
    const int r0 = tm * 256 + wm * 128 + m * 16 + fq * 4;
#pragma unroll
    for (int n = 0; n < 4; ++n) {
      const int c = tn * 256 + wn * 64 + n * 16 + fr;
      const float uc = ub[c];
      const float wc = wb[c] + bias[c];
#pragma unroll
      for (int j = 0; j < 4; ++j) {
        const int r = r0 + j;
        const float rs = rstdb[r], mn = meanb[r];
        const size_t idx = (size_t)r * 1024 + c;
        outf[idx] = rs * acc[m][n][j] - rs * mn * uc + wc + resid[idx];
      }
    }
  }
}

// ---------------- attention: one block per (b,h); 4 waves, each owns 16 q-rows ----------------
__global__ __launch_bounds__(256) void attn_kernel(const u16* __restrict__ Qb,
                                                   const u16* __restrict__ Kb,
                                                   const u16* __restrict__ Vt,
                                                   u16* __restrict__ AO) {
  __shared__ u16 Qs[64 * 64];    // 8 KB  (i,d)
  __shared__ u16 Ks[256 * 64];   // 32 KB (t,d), reused as P (i,t) later
  __shared__ u16 Vs[64 * 256];   // 32 KB (d,t)
  const int bh = blockIdx.x;
  const int tid = threadIdx.x, lane = tid & 63, wv = tid >> 6;
  const u16* qsrc = Qb + (size_t)bh * 4096;
  const u16* ksrc = Kb + (size_t)bh * 16384;
  const u16* vsrc = Vt + (size_t)bh * 16384;
  // stage Q,K first; V issued but NOT waited before QK^T (overlap)
#pragma unroll
  for (int i = 0; i < 2; ++i) gl16(qsrc + (i * 256 + tid) * 8, &Qs[(i * 256 + tid) * 8]);
#pragma unroll
  for (int i = 0; i < 8; ++i) gl16(ksrc + (i * 256 + tid) * 8, &Ks[(i * 256 + tid) * 8]);
#pragma unroll
  for (int i = 0; i < 8; ++i) gl16(vsrc + (i * 256 + tid) * 8, &Vs[(i * 256 + tid) * 8]);
  asm volatile("s_waitcnt vmcnt(8)" ::: "memory");  // Q+K resident; V (8) in flight
  __builtin_amdgcn_s_barrier();

  f32x4 sacc[16];
  const f32x4 z = {0.f, 0.f, 0.f, 0.f};
#pragma unroll
  for (int n = 0; n < 16; ++n) sacc[n] = z;
#pragma unroll
  for (int s = 0; s < 2; ++s) {
    const bf16x8 aq = *(const bf16x8*)&Qs[(wv * 16 + (lane & 15)) * 64 + s * 32 + (lane >> 4) * 8];
#pragma unroll
    for (int n = 0; n < 16; ++n) {
      const bf16x8 bk = *(const bf16x8*)&Ks[(n * 16 + (lane & 15)) * 64 + s * 32 + (lane >> 4) * 8];
      sacc[n] = mfma16(aq, bk, sacc[n]);
    }
  }

  // mask + softmax; keep P unnormalized, fold 1/sum into O-write
  const int rgrp = lane >> 4, cl = lane & 15;
  float inv[4];
#pragma unroll
  for (int j = 0; j < 4; ++j) {
    const int qrow = (wv << 4) + (rgrp << 2) + j;
    float m_ = -1e30f;
#pragma unroll
    for (int n = 0; n < 16; ++n) {
      const int col = (n << 4) + cl;
      float sv = sacc[n][j] * 0.125f;
      sv = ((col >> 2) <= qrow) ? sv : -1e30f;
      sacc[n][j] = sv;
      m_ = fmaxf(m_, sv);
    }
#pragma unroll
    for (int off = 8; off; off >>= 1) m_ = fmaxf(m_, __shfl_xor(m_, off, 64));
    float s_ = 0.f;
#pragma unroll
    for (int n = 0; n < 16; ++n) {
      const float p = exp2f((sacc[n][j] - m_) * 1.44269504f);
      sacc[n][j] = p;
      s_ += p;
    }
#pragma unroll
    for (int off = 8; off; off >>= 1) s_ += __shfl_xor(s_, off, 64);
    inv[j] = 1.0f / s_;
  }

  asm volatile("s_waitcnt vmcnt(0)" ::: "memory");  // V resident
  __builtin_amdgcn_s_barrier();                     // all waves past QK reads of Ks
  u16* Ps = Ks;                                     // reuse as P~ (i,t) row-major
#pragma unroll
  for (int n = 0; n < 16; ++n)
#pragma unroll
    for (int j = 0; j < 4; ++j)
      Ps[((wv << 4) + (rgrp << 2) + j) * 256 + (n << 4) + cl] = f2bf(sacc[n][j]);
  __syncthreads();

  f32x4 oacc[4];
#pragma unroll
  for (int n = 0; n < 4; ++n) oacc[n] = z;
#pragma unroll
  for (int ks = 0; ks < 8; ++ks) {
    const bf16x8 ap = *(const bf16x8*)&Ps[(wv * 16 + (lane & 15)) * 256 + ks * 32 + (lane >> 4) * 8];
#pragma unroll
    for (int n = 0; n < 4; ++n) {
      const bf16x8 bv = *(const bf16x8*)&Vs[(n * 16 + (lane & 15)) * 256 + ks * 32 + (lane >> 4) * 8];
      oacc[n] = mfma16(ap, bv, oacc[n]);
    }
  }
  const int b = bh >> 4, h = bh & 15;
  u16* obase = AO + (size_t)b * 65536 + (size_t)h * 64;
#pragma unroll
  for (int n = 0; n < 4; ++n)
#pragma unroll
    for (int j = 0; j < 4; ++j) {
      const int qrow = (wv << 4) + (rgrp << 2) + j;
      const int d = (n << 4) + cl;
      obase[(size_t)qrow * 1024 + d] = f2bf(oacc[n][j] * inv[j]);
    }
}

// ---------------- launch ----------------
extern "C" void kernel_launch(void* const* d_in, const int* in_sizes, int n_in,
                              void* d_out, int out_size, void* d_ws, size_t ws_size,
                              hipStream_t stream) {
  const float* x     = (const float*)d_in[0];
  const float* lat   = (const float*)d_in[1];
  const float* Wq    = (const float*)d_in[2];
  const float* Wk    = (const float*)d_in[3];
  const float* Wv    = (const float*)d_in[4];
  const float* Wo    = (const float*)d_in[5];
  const float* bo    = (const float*)d_in[6];
  const float* g_out = (const float*)d_in[7];
  const float* b_out = (const float*)d_in[8];
  const float* g_x   = (const float*)d_in[9];
  const float* b_x   = (const float*)d_in[10];
  const float* g_l   = (const float*)d_in[11];
  const float* b_l   = (const float*)d_in[12];
  float* out = (float*)d_out;

  char* W = (char*)d_ws;
  u16* wqb = (u16*)(W + 0);            // 2 MiB each, contiguous
  u16* wkb = (u16*)(W + 2097152);
  u16* wvb = (u16*)(W + 4194304);      // contiguous after wkb (merged B indexing)
  u16* wob = (u16*)(W + 6291456);      // bf16(g_out ⊙ Wo)
  u16* lnl = (u16*)(W + 8388608);      // 32 MiB
  u16* lnx = (u16*)(W + 41943040);     // 128 MiB
  u16* qb  = (u16*)(W + 176160768);    // 32 MiB
  u16* kb  = (u16*)(W + 209715200);    // 128 MiB
  u16* vt  = (u16*)(W + 343932928);    // 128 MiB
  u16* ao  = lnx;                      // alias: lnx dead after gemm_qkv
  // qb dead after attn: reuse for stats outputs
  float* meanb = (float*)qb;                       // 64 KiB
  float* rstdb = (float*)((char*)qb + 65536);      // 64 KiB
  float* ub    = (float*)((char*)qb + 131072);     // 4 KiB
  float* wb    = (float*)((char*)qb + 135168);     // 4 KiB
  (void)wvb;

  fused_pre<<<86016, 256, 0, stream>>>(Wq, Wk, Wv, Wo, wqb, wob, g_out,
                                       lat, g_l, b_l, lnl,
                                       x, g_x, b_x, lnx);

  gemm_qkv<<<2304, 512, 0, stream>>>(lnx, lnl, wkb, wqb, kb, vt, qb);

  attn_kernel<<<4096, 256, 0, stream>>>(qb, kb, vt, ao);

  stats_kernel<<<17408, 256, 0, stream>>>(ao, meanb, rstdb, Wo, g_out, b_out, ub, wb);

  gemm_out<<<256, 512, 0, stream>>>(ao, wob, ub, wb, bo, meanb, rstdb, lat, out);
}